// Round 10
// baseline (102.155 us; speedup 1.0000x reference)
//
#include <hip/hip_runtime.h>

#define W 2048
#define H 2048
#define TX 64
#define TY 32
#define DW 92          // Ds row stride (floats); f4 row stride 23
#define DH 52          // TY + 20
#define HS 88          // Hs row stride; f4 row stride 22
// Ds col lc <-> img col gj = j0 - 12 + lc (lc 0..87); Ds row li <-> img row gi = i0 - 10 + li
// Hs (pass1): H[r][hl] = hsum5(D[r]) centered at img col j0 - 8 + hl (hl 0..79)
// Hs (pass2, reused): V2[w][vl] = vsum5(D2) at img col j0 - 8 + vl, out row i0 + w

typedef float f4 __attribute__((ext_vector_type(4)));

// DIAGNOSTIC BUILD: identical algorithm to R9, body executed twice per dispatch
// (rep loop) so the dispatch exceeds the 43us harness fills and surfaces in
// rocprof top-5 with real counters. True kernel time = dur/2.
__global__ __launch_bounds__(512, 8) void guided_fused(const float* __restrict__ X,
                                                       const float* __restrict__ y,
                                                       float* __restrict__ out) {
    __shared__ __align__(16) float Ds[DH * DW];   // 19.1 KB: D, then D2 in-place (rows 8..43)
    __shared__ __align__(16) float Hs[DH * HS];   // 18.3 KB: H (pass1), then V2 (pass2)

    const int tid = threadIdx.x;
    const int bx = blockIdx.x, by = blockIdx.y;
    const int i0 = by * TY, j0 = bx * TX;
    const bool interior = (bx >= 1) & (bx <= 30) & (by >= 1) & (by <= 62);
    const float R85 = 0.011764706f;               // 1/85

    for (int rep = 0; rep < 2; ++rep) {

    // ---- S1: D = y - X over 52 rows x 22 aligned f4 col-groups ----
    if (interior) {
        #pragma unroll
        for (int k = 0; k < 3; ++k) {
            int c = tid + k * 512;
            if (c < DH * 22) {
                int li = c / 22, g = c - li * 22;
                int off = (i0 - 10 + li) * W + (j0 - 12) + 4 * g;   // 16B aligned
                f4 yv = *(const f4*)&y[off];
                f4 xv = *(const f4*)&X[off];
                *(f4*)&Ds[li * DW + 4 * g] = yv - xv;
            }
        }
    } else {
        #pragma unroll
        for (int k = 0; k < 3; ++k) {
            int c = tid + k * 512;
            if (c < DH * 22) {
                int li = c / 22, g = c - li * 22;
                int gi = i0 - 10 + li, gj = j0 - 12 + 4 * g;
                f4 d = {0.f, 0.f, 0.f, 0.f};
                if ((unsigned)gi < H) {
                    if (gj >= 0 && gj + 3 < W) {
                        f4 yv = *(const f4*)&y[gi * W + gj];
                        f4 xv = *(const f4*)&X[gi * W + gj];
                        d = yv - xv;
                    } else {
                        #pragma unroll
                        for (int e = 0; e < 4; ++e) {
                            int gc = gj + e;
                            if ((unsigned)gc < W) d[e] = y[gi * W + gc] - X[gi * W + gc];
                        }
                    }
                }
                *(f4*)&Ds[li * DW + 4 * g] = d;
            }
        }
    }
    __syncthreads();

    // ---- S2: H[r][4g..4g+3] = hsum5(D row r); 1040 tasks ----
    #pragma unroll
    for (int k = 0; k < 3; ++k) {
        int c = tid + k * 512;
        if (c < DH * 20) {
            int r = c / 20, g = c - r * 20;
            const f4* dp = (const f4*)&Ds[r * DW + 4 * g];
            f4 a = dp[0], b = dp[1], cc = dp[2];
            float sb123 = b.y + b.z;
            float h = b.x + sb123;
            f4 o;
            o.x = a.z + a.w + h;
            o.y = a.w + h + b.w;
            o.z = h + b.w + cc.x;
            o.w = sb123 + b.w + cc.x + cc.y;
            *(f4*)&Hs[r * HS + 4 * g] = o;
        }
    }
    __syncthreads();

    // ---- S3: D2 = D - vsum17(H)/Ni1, in-place f4 RMW; 180 tasks ----
    if (tid < 180) {
        int seg = tid / 20, g = tid - seg * 20;
        int v0 = seg * 4;
        const f4* hp = (const f4*)&Hs[v0 * HS + 4 * g];
        f4 r0 = hp[0], r1 = hp[22], r2 = hp[44];
        f4 s = r0 + r1 + r2;
        #pragma unroll
        for (int t = 3; t < 17; ++t) s += hp[t * 22];
        #pragma unroll
        for (int k = 0; k < 4; ++k) {
            int v = v0 + k;
            int off = (v + 8) * DW + 4 * g + 4;
            f4 d2 = *(const f4*)&Ds[off];
            if (interior) {
                d2 -= s * R85;
            } else {
                int gi = i0 + v - 2;
                if ((unsigned)gi < H) {
                    int r0c = gi - 8 > 0 ? gi - 8 : 0;
                    int r1c = gi + 8 < H - 1 ? gi + 8 : H - 1;
                    float rowsN = (float)(r1c - r0c + 1);
                    #pragma unroll
                    for (int e = 0; e < 4; ++e) {
                        int gj = j0 - 8 + 4 * g + e;
                        if ((unsigned)gj < W) {
                            int c0 = gj - 2 > 0 ? gj - 2 : 0;
                            int c1 = gj + 2 < W - 1 ? gj + 2 : W - 1;
                            d2[e] -= s[e] * __builtin_amdgcn_rcpf(rowsN * (float)(c1 - c0 + 1));
                        }
                    }
                }
            }
            *(f4*)&Ds[off] = d2;
            if (k < 3) s += hp[(k + 17) * 22] - hp[k * 22];
        }
    }
    __syncthreads();

    // ---- S4: V2[w] = vsum5(D2 rows w..w+4); 320 tasks ----
    if (tid < 320) {
        int seg = tid / 20, g = tid - seg * 20;
        int w0 = seg * 2;
        const f4* dp = (const f4*)&Ds[(w0 + 8) * DW + 4 * g + 4];
        f4 r0 = dp[0];
        f4 s = r0 + dp[23] + dp[46] + dp[69] + dp[92];
        f4* vp = (f4*)&Hs[w0 * HS + 4 * g];
        vp[0] = s;
        s += dp[115] - r0; vp[22] = s;
    }
    __syncthreads();

    // ---- S5: out = y - D2 + hsum17(V2)/Ni2; 512 tasks ----
    {
        int w = tid >> 4, x0 = (tid & 15) * 4;
        int gbase = (i0 + w) * W + j0 + x0;
        f4 yv = *(const f4*)&y[gbase];
        float val[20];
        const f4* vp = (const f4*)&Hs[w * HS + x0];
        #pragma unroll
        for (int q = 0; q < 5; ++q) {
            f4 tq = vp[q];
            val[q * 4 + 0] = tq.x; val[q * 4 + 1] = tq.y;
            val[q * 4 + 2] = tq.z; val[q * 4 + 3] = tq.w;
        }
        float s = 0.f;
        #pragma unroll
        for (int c = 0; c < 17; ++c) s += val[c];
        f4 d2 = *(const f4*)&Ds[(w + 10) * DW + x0 + 12];
        f4 o;
        if (interior) {
            o.x = yv.x - d2.x + s * R85;
            s += val[17] - val[0];
            o.y = yv.y - d2.y + s * R85;
            s += val[18] - val[1];
            o.z = yv.z - d2.z + s * R85;
            s += val[19] - val[2];
            o.w = yv.w - d2.w + s * R85;
        } else {
            int gi = i0 + w;
            int r0c = gi - 2 > 0 ? gi - 2 : 0;
            int r1c = gi + 2 < H - 1 ? gi + 2 : H - 1;
            float rowsN = (float)(r1c - r0c + 1);
            float res[4];
            #pragma unroll
            for (int e = 0; e < 4; ++e) {
                int gj = j0 + x0 + e;
                int c0 = gj - 8 > 0 ? gj - 8 : 0;
                int c1 = gj + 8 < W - 1 ? gj + 8 : W - 1;
                res[e] = s * __builtin_amdgcn_rcpf(rowsN * (float)(c1 - c0 + 1));
                if (e < 3) s += val[e + 17] - val[e];
            }
            o.x = yv.x - d2.x + res[0];
            o.y = yv.y - d2.y + res[1];
            o.z = yv.z - d2.z + res[2];
            o.w = yv.w - d2.w + res[3];
        }
        *(f4*)&out[gbase] = o;
    }
    __syncthreads();   // protect Ds/Hs before next rep's S1 overwrite

    } // rep
}

extern "C" void kernel_launch(void* const* d_in, const int* in_sizes, int n_in,
                              void* d_out, int out_size, void* d_ws, size_t ws_size,
                              hipStream_t stream) {
    const float* X = (const float*)d_in[0];
    const float* y = (const float*)d_in[1];
    float* out = (float*)d_out;

    dim3 blk(512, 1, 1);
    dim3 grd(W / TX, H / TY, 1);   // 32 x 64 = 2048 blocks
    guided_fused<<<grd, blk, 0, stream>>>(X, y, out);
}